// Round 3
// baseline (126.158 us; speedup 1.0000x reference)
//
#include <hip/hip_runtime.h>
#include <hip/hip_bf16.h>

// SEQ=512, BATCH=64, DIM=512, MAXLEN=512, E=655360
// out[b][u][s] = edge(b,u,s) ? exp(scale) / (T_e + 1e-10*(T-T_e)) : 0   (max cancels)
// scale[s,b,m] = sum_d M[s,b,d] * W[m,d]
// Structure: one block = (b, m-tile 128) x full s=512. W-tile resident in LDS
// (XOR-swizzled, loaded once); M streamed global->reg per fragment (no barriers
// in K-loop); epilogue does sum-only softmax + edge renorm with one LDS reduce.

#define SEQ 512
#define BATCH 64
#define DIM 512
#define MAXLEN 512

typedef __attribute__((ext_vector_type(8))) __bf16 bf16x8;
typedef __attribute__((ext_vector_type(4))) float f32x4;

__device__ __forceinline__ unsigned cvt_pk(float lo, float hi) {
    unsigned r;
    asm("v_cvt_pk_bf16_f32 %0, %1, %2" : "=v"(r) : "v"(lo), "v"(hi));
    return r;
}

// ---------------- edge bitmap scatter ----------------
__global__ __launch_bounds__(256) void edge_scatter(const int* __restrict__ eb,
                                                    const int* __restrict__ eu,
                                                    const int* __restrict__ ev,
                                                    unsigned int* __restrict__ bits,
                                                    int E) {
    int i = blockIdx.x * 256 + threadIdx.x;
    if (i < E) {
        int b = eb[i], u = eu[i], v = ev[i];
        atomicOr(&bits[(b * MAXLEN + u) * 16 + (v >> 5)], 1u << (v & 31));
    }
}

// ---------------- fused GEMM + softmax + edge renorm ----------------
__global__ __launch_bounds__(512, 2) void fused_attn(const float* __restrict__ Mg,
                                                     const float* __restrict__ Wg,
                                                     const unsigned int* __restrict__ bitsG,
                                                     float* __restrict__ out) {
    __shared__ __align__(16) char Wt[128 * 1024];  // 128 rows x 512 bf16, XOR-swizzled
    __shared__ float2 red[128][4];                 // (T, Te) partials per s-quarter

    // XCD-concentrating remap: same-XCD blocks share b's -> M_b L2-resident
    const int g = blockIdx.x;
    const int work = (g & 7) * 32 + (g >> 3);   // bijective over [0,256)
    const int b  = work >> 2;
    const int m0 = (work & 3) * 128;

    const int t    = threadIdx.x;
    const int lane = t & 63;
    const int wv   = t >> 6;       // 0..7
    const int wm   = wv >> 2;      // m half (64 rows)
    const int ws   = wv & 3;       // s quarter (128 cols)
    const int lg   = lane >> 4;    // 0..3
    const int lc   = lane & 15;

    // ---- one-time W tile load: 128x512 f32 -> bf16, swizzled LDS ----
    {
        const char* wbase = reinterpret_cast<const char*>(Wg + (size_t)m0 * DIM);
#pragma unroll 8
        for (int it = 0; it < 32; ++it) {
            int f = it * 512 + t;            // float4 index 0..16383
            int row = f >> 7;                // 0..127
            int cb  = (f & 127) * 16;        // byte offset within f32 row
            float4 v = *reinterpret_cast<const float4*>(wbase + (size_t)row * 2048 + cb);
            unsigned p0 = cvt_pk(v.x, v.y), p1 = cvt_pk(v.z, v.w);
            unsigned byte = (unsigned)(row * 1024 + cb / 2) ^ ((row & 7) << 4);
            *reinterpret_cast<uint2*>(Wt + byte) = make_uint2(p0, p1);
        }
    }
    __syncthreads();   // the ONLY barrier before the epilogue

    f32x4 acc[4][8] = {};   // [m-frag][s-frag]
    const float* mb = Mg + (size_t)b * DIM;   // &M[0][b][0]; s-row stride = BATCH*DIM

    for (int k0 = 0; k0 < DIM; k0 += 32) {
        bf16x8 bfr[8];
#pragma unroll
        for (int j = 0; j < 8; ++j) {
            const float* p = mb + (size_t)(ws * 128 + j * 16 + lc) * (BATCH * DIM) + k0 + lg * 8;
            float4 r0 = *reinterpret_cast<const float4*>(p);
            float4 r1 = *reinterpret_cast<const float4*>(p + 4);
            uint4 pk;
            pk.x = cvt_pk(r0.x, r0.y); pk.y = cvt_pk(r0.z, r0.w);
            pk.z = cvt_pk(r1.x, r1.y); pk.w = cvt_pk(r1.z, r1.w);
            bfr[j] = __builtin_bit_cast(bf16x8, pk);
        }
        bf16x8 af[4];
#pragma unroll
        for (int i = 0; i < 4; ++i) {
            int arow = wm * 64 + i * 16 + lc;
            unsigned byte = (unsigned)(arow * 1024 + k0 * 2 + lg * 16) ^ ((arow & 7) << 4);
            af[i] = *reinterpret_cast<const bf16x8*>(Wt + byte);
        }
#pragma unroll
        for (int i = 0; i < 4; ++i)
#pragma unroll
            for (int j = 0; j < 8; ++j)
                acc[i][j] = __builtin_amdgcn_mfma_f32_16x16x32_bf16(af[i], bfr[j], acc[i][j], 0, 0, 0);
    }

    // ---- epilogue: sum-only softmax (max cancels) + edge renorm ----
#pragma unroll
    for (int i = 0; i < 4; ++i) {
#pragma unroll
        for (int r = 0; r < 4; ++r) {
            int ml = wm * 64 + i * 16 + lg * 4 + r;
            uint4 w4 = *reinterpret_cast<const uint4*>(
                bitsG + ((size_t)(b * MAXLEN + m0 + ml)) * 16 + ws * 4);
            float T = 0.f, Te = 0.f;
#pragma unroll
            for (int j = 0; j < 8; ++j) {
                float e = __expf(acc[i][j][r]);
                acc[i][j][r] = e;
                unsigned word = (j < 2) ? w4.x : (j < 4) ? w4.y : (j < 6) ? w4.z : w4.w;
                float bit = (float)((word >> ((j & 1) * 16 + lc)) & 1u);
                T += e; Te += e * bit;
            }
#pragma unroll
            for (int off = 1; off < 16; off <<= 1) {
                T  += __shfl_xor(T, off);
                Te += __shfl_xor(Te, off);
            }
            if (lc == 0) red[ml][ws] = make_float2(T, Te);
        }
    }
    __syncthreads();

#pragma unroll
    for (int i = 0; i < 4; ++i) {
#pragma unroll
        for (int r = 0; r < 4; ++r) {
            int ml = wm * 64 + i * 16 + lg * 4 + r;
            float2 p0 = red[ml][0], p1 = red[ml][1], p2 = red[ml][2], p3 = red[ml][3];
            float T  = p0.x + p1.x + p2.x + p3.x;
            float Te = p0.y + p1.y + p2.y + p3.y;
            float inv = 1.0f / (Te + 1e-10f * (T - Te));
            uint4 w4 = *reinterpret_cast<const uint4*>(
                bitsG + ((size_t)(b * MAXLEN + m0 + ml)) * 16 + ws * 4);
            size_t base = ((size_t)(b * MAXLEN + m0 + ml)) * SEQ + ws * 128 + lc;
#pragma unroll
            for (int j = 0; j < 8; ++j) {
                unsigned word = (j < 2) ? w4.x : (j < 4) ? w4.y : (j < 6) ? w4.z : w4.w;
                unsigned bit = (word >> ((j & 1) * 16 + lc)) & 1u;
                out[base + (size_t)j * 16] = bit ? acc[i][j][r] * inv : 0.0f;
            }
        }
    }
}

extern "C" void kernel_launch(void* const* d_in, const int* in_sizes, int n_in,
                              void* d_out, int out_size, void* d_ws, size_t ws_size,
                              hipStream_t stream) {
    const float* Mg = (const float*)d_in[0];
    const float* Wg = (const float*)d_in[1];
    // d_in[2] = lengths (unused by reference)
    const int* eb = (const int*)d_in[3];
    const int* eu = (const int*)d_in[4];
    const int* ev = (const int*)d_in[5];
    const int E = in_sizes[3];

    float* out = (float*)d_out;
    unsigned int* bits = (unsigned int*)d_ws;   // 32768 rows * 16 words = 2 MB

    hipMemsetAsync(bits, 0, (size_t)BATCH * MAXLEN * 16 * sizeof(unsigned int), stream);
    edge_scatter<<<(E + 255) / 256, 256, 0, stream>>>(eb, eu, ev, bits, E);
    fused_attn<<<256, 512, 0, stream>>>(Mg, Wg, bits, out);
}